// Round 6
// baseline (117.631 us; speedup 1.0000x reference)
//
#include <hip/hip_runtime.h>
#include <hip/hip_bf16.h>

#define NEXP 16
#define KDIM 1024
#define ODIM 4096
#define NTOK 2048

#define BM   256                    // token rows resident per block
#define BN   256                    // output cols per block (8 waves x 32)
#define KC   64                     // K-chunk in LDS per phase
#define NPH  (KDIM / KC)            // 16 phases
#define NBLK (NEXP * (ODIM / BN))   // 256 blocks = 1 per CU

typedef __attribute__((ext_vector_type(8))) short short8;
typedef __attribute__((ext_vector_type(4))) float f32x4;
typedef __attribute__((ext_vector_type(4))) unsigned short u16x4;

__device__ __forceinline__ unsigned short f2bf(float f) {
    __hip_bfloat16 h = __float2bfloat16(f);
    return __builtin_bit_cast(unsigned short, h);
}

__device__ __forceinline__ short8 pack8(float4 a, float4 b) {
    short8 r;
    r[0] = (short)f2bf(a.x); r[1] = (short)f2bf(a.y);
    r[2] = (short)f2bf(a.z); r[3] = (short)f2bf(a.w);
    r[4] = (short)f2bf(b.x); r[5] = (short)f2bf(b.y);
    r[6] = (short)f2bf(b.z); r[7] = (short)f2bf(b.w);
    return r;
}

__device__ __forceinline__ u16x4 pack4(float4 a) {
    u16x4 o;
    o[0] = f2bf(a.x); o[1] = f2bf(a.y); o[2] = f2bf(a.z); o[3] = f2bf(a.w);
    return o;
}

// ---------------------------------------------------------------------------
// Kernel 1: deterministic counting sort of tokens by expert (unchanged).
// ---------------------------------------------------------------------------
__global__ __launch_bounds__(256) void moe_sort(const int* __restrict__ gate,
                                                int* __restrict__ perm,
                                                int* __restrict__ offs) {
    __shared__ int lgate[NTOK];
    __shared__ int hist[256][NEXP + 1];
    __shared__ int base[NEXP];
    const int t = threadIdx.x;
    for (int i = t; i < NTOK; i += 256) lgate[i] = gate[i];
    #pragma unroll
    for (int e = 0; e < NEXP; ++e) hist[t][e] = 0;
    __syncthreads();
    const int TPT = NTOK / 256;
    for (int j = 0; j < TPT; ++j) hist[t][lgate[t * TPT + j]]++;
    __syncthreads();
    if (t < NEXP) {
        int s = 0;
        for (int i = 0; i < 256; ++i) { int v = hist[i][t]; hist[i][t] = s; s += v; }
        base[t] = s;
    }
    __syncthreads();
    if (t == 0) {
        int s = 0;
        for (int e = 0; e < NEXP; ++e) { int v = base[e]; base[e] = s; offs[e] = s; s += v; }
        offs[NEXP] = s;
    }
    __syncthreads();
    #pragma unroll
    for (int e = 0; e < NEXP; ++e) hist[t][e] += base[e];
    for (int j = 0; j < TPT; ++j) {
        int tok = t * TPT + j;
        int e = lgate[tok];
        int pos = hist[t][e]++;
        perm[pos] = tok;
    }
}

// ---------------------------------------------------------------------------
// Kernel 1.5: gather+convert A to bf16 in perm order (unchanged).
// ---------------------------------------------------------------------------
__global__ __launch_bounds__(256) void moe_cvt(const float* __restrict__ inp,
                                               const int* __restrict__ perm,
                                               unsigned short* __restrict__ A2) {
    const int pos = blockIdx.x;
    const int tok = perm[pos];
    const float4* src = (const float4*)(inp + (size_t)tok * KDIM);
    u16x4* dst = (u16x4*)(A2 + (size_t)pos * KDIM);
    float4 v = src[threadIdx.x];
    dst[threadIdx.x] = pack4(v);
}

// ---------------------------------------------------------------------------
// Kernel 2: A-resident grouped GEMM, W read once AND coalesced.
// R5 lesson: direct-to-register W fragments are a 16-row scatter (64 narrow
// segments/instr) -> TA-bound. Now W stages through LDS bf16: load map
// slot=t&15,row=t>>4 -> 16 lanes cover 256B contiguous of one W row (full
// 128B lines), 8 passes per phase. Fragments then read from LDS with the
// measured-0-conflict pattern ([row][64] bf16, oct ^ (row&7) swizzle).
// LDS: A dbuf 64KB + B dbuf 64KB = 128KB, 1 block/CU, 8 waves = 8 col-groups.
// Phase barriers are lgkmcnt-only; next-phase global loads stay in flight.
// ---------------------------------------------------------------------------
template <bool PRE>
__global__ __launch_bounds__(512, 1) void moe_gemm(
    const float* __restrict__ inp,
    const unsigned short* __restrict__ A2,
    const float* __restrict__ weight,
    const int* __restrict__ perm,
    const int* __restrict__ offs,
    float* __restrict__ out)
{
    const int bid = blockIdx.x;
    const int v   = (bid & 7) * (NBLK / 8) + (bid >> 3); // 32 consec per XCD = 2 experts
    const int e   = v >> 4;                              // 16 oc-tiles per expert
    const int oc  = (v & 15) * BN;

    const int beg = offs[e], end = offs[e + 1];
    const int nall = end - beg;
    if (nall <= 0) return;

    __shared__ short As[2][BM][KC];    // 64 KB bf16
    __shared__ short Bs[2][BN][KC];    // 64 KB bf16

    const int t    = threadIdx.x;      // 0..511
    const int lane = t & 63;
    const int wn   = t >> 6;           // 0..7 col-group
    const int frow = lane & 15;
    const int fks  = lane >> 4;        // 0..3

    // A staging map: thread t = k-octet (t&7) of rows {t>>3 (+64i)}
    const int sko = t & 7;
    const int srb = t >> 3;            // 0..63

    // B staging map: slot=t&15 (16B granule of the 256B phase-row), row=t>>4
    const int bslot = t & 15;
    const int brow0 = t >> 4;          // 0..31; passes add 32
    const int boct  = bslot >> 1;      // 16B bf16 octet index after cvt
    const int bhalf = bslot & 1;
    const float* bsrc = weight + ((size_t)e * ODIM + oc + brow0) * KDIM + bslot * 4;

#define BARRIER() do {                                            \
        __builtin_amdgcn_sched_barrier(0);                        \
        asm volatile("s_waitcnt lgkmcnt(0)" ::: "memory");        \
        __builtin_amdgcn_s_barrier();                             \
        __builtin_amdgcn_sched_barrier(0);                        \
    } while (0)

    for (int base = 0; base < nall; base += BM) {
        const int rows = (nall - base < BM) ? (nall - base) : BM;
        const int c0   = beg + base;
        const int mfrags = (rows + 15) >> 4;   // active 16-row fragments

        // clamped A source rows (unconditional loads)
        const unsigned short* ap2[4];
        const float*          apf[4];
        #pragma unroll
        for (int i = 0; i < 4; ++i) {
            int r = srb + 64 * i; if (r > rows - 1) r = rows - 1;
            if (PRE) ap2[i] = A2 + (size_t)(c0 + r) * KDIM + sko * 8;
            else     apf[i] = inp + (size_t)perm[c0 + r] * KDIM + sko * 8;
        }

        f32x4 acc[16][2];
        #pragma unroll
        for (int m = 0; m < 16; ++m) {
            acc[m][0] = (f32x4){0.f, 0.f, 0.f, 0.f};
            acc[m][1] = (f32x4){0.f, 0.f, 0.f, 0.f};
        }

        short8 sv0, sv1, sv2, sv3;                      // A staging (PRE)
        float4 fa0, fb0, fa1, fb1, fa2, fb2, fa3, fb3;  // A staging (!PRE)
        float4 Bv0, Bv1, Bv2, Bv3, Bv4, Bv5, Bv6, Bv7;  // B staging (8 passes)

#define ISSUE_A(kc) {                                                    \
        if (PRE) {                                                       \
            sv0 = *(const short8*)(ap2[0] + (kc));                       \
            sv1 = *(const short8*)(ap2[1] + (kc));                       \
            sv2 = *(const short8*)(ap2[2] + (kc));                       \
            sv3 = *(const short8*)(ap2[3] + (kc));                       \
        } else {                                                         \
            fa0 = *(const float4*)(apf[0] + (kc));                       \
            fb0 = *(const float4*)(apf[0] + (kc) + 4);                   \
            fa1 = *(const float4*)(apf[1] + (kc));                       \
            fb1 = *(const float4*)(apf[1] + (kc) + 4);                   \
            fa2 = *(const float4*)(apf[2] + (kc));                       \
            fb2 = *(const float4*)(apf[2] + (kc) + 4);                   \
            fa3 = *(const float4*)(apf[3] + (kc));                       \
            fb3 = *(const float4*)(apf[3] + (kc) + 4);                   \
        }                                                                \
    }

#define CVTWRITE_A(buf) {                                                          \
        int r0 = srb;                                                              \
        int r1 = srb + 64;                                                         \
        int r2 = srb + 128;                                                        \
        int r3 = srb + 192;                                                        \
        *(short8*)&As[buf][r0][(sko ^ (r0 & 7)) * 8] = PRE ? sv0 : pack8(fa0, fb0);\
        *(short8*)&As[buf][r1][(sko ^ (r1 & 7)) * 8] = PRE ? sv1 : pack8(fa1, fb1);\
        *(short8*)&As[buf][r2][(sko ^ (r2 & 7)) * 8] = PRE ? sv2 : pack8(fa2, fb2);\
        *(short8*)&As[buf][r3][(sko ^ (r3 & 7)) * 8] = PRE ? sv3 : pack8(fa3, fb3);\
    }

#define ISSUE_B(kc) {                                             \
        Bv0 = *(const float4*)(bsrc + (kc));                      \
        Bv1 = *(const float4*)(bsrc + (kc) + (size_t)32 * KDIM);  \
        Bv2 = *(const float4*)(bsrc + (kc) + (size_t)64 * KDIM);  \
        Bv3 = *(const float4*)(bsrc + (kc) + (size_t)96 * KDIM);  \
        Bv4 = *(const float4*)(bsrc + (kc) + (size_t)128 * KDIM); \
        Bv5 = *(const float4*)(bsrc + (kc) + (size_t)160 * KDIM); \
        Bv6 = *(const float4*)(bsrc + (kc) + (size_t)192 * KDIM); \
        Bv7 = *(const float4*)(bsrc + (kc) + (size_t)224 * KDIM); \
    }

#define BW1(buf, p, V) {                                                       \
        int rw = brow0 + 32 * (p);                                             \
        *(u16x4*)(&Bs[buf][0][0] + rw * 64 + (boct ^ (rw & 7)) * 8 + bhalf * 4)\
            = pack4(V);                                                        \
    }
#define CVTWRITE_B(buf) {                                                      \
        BW1(buf, 0, Bv0); BW1(buf, 1, Bv1); BW1(buf, 2, Bv2); BW1(buf, 3, Bv3);\
        BW1(buf, 4, Bv4); BW1(buf, 5, Bv5); BW1(buf, 6, Bv6); BW1(buf, 7, Bv7);\
    }

#define STEP(pb, s) {                                                          \
        const int ko_r = (s) * 4 + fks;                                        \
        const int rb0 = wn * 32 + frow;                                        \
        const int rb1 = rb0 + 16;                                              \
        short8 bf0 = *(const short8*)(&Bs[pb][0][0] + rb0 * 64 + ((ko_r ^ (rb0 & 7)) * 8)); \
        short8 bf1 = *(const short8*)(&Bs[pb][0][0] + rb1 * 64 + ((ko_r ^ (rb1 & 7)) * 8)); \
        _Pragma("unroll")                                                      \
        for (int m = 0; m < 16; ++m) {                                         \
            if (m < mfrags) {                                                  \
                int row = m * 16 + frow;                                       \
                short8 af = *(const short8*)&As[pb][row][(ko_r ^ (row & 7)) * 8]; \
                acc[m][0] = __builtin_amdgcn_mfma_f32_16x16x32_bf16(af, bf0, acc[m][0], 0, 0, 0); \
                acc[m][1] = __builtin_amdgcn_mfma_f32_16x16x32_bf16(af, bf1, acc[m][1], 0, 0, 0); \
            }                                                                  \
        }                                                                      \
    }

        // ---- prologue: phase 0 staged (unhidden once per base-chunk) ----
        ISSUE_A(0);
        ISSUE_B(0);
        CVTWRITE_A(0);
        CVTWRITE_B(0);
        BARRIER();

        // ---- phases 0..14 with next-phase prefetch ----
        for (int p = 0; p < NPH - 1; ++p) {
            const int pb = p & 1;
            const int kn = (p + 1) * KC;
            ISSUE_A(kn);
            ISSUE_B(kn);
            STEP(pb, 0);
            STEP(pb, 1);
            __builtin_amdgcn_sched_barrier(0);
            CVTWRITE_A(pb ^ 1);        // vmcnt waits land here, post-MFMA
            CVTWRITE_B(pb ^ 1);
            BARRIER();
        }
        // ---- final phase: no prefetch, no junk loads ----
        STEP(1, 0);
        STEP(1, 1);

        // ---- epilogue: C layout col=lane&15, row=(lane>>4)*4+reg ----
        const int col0 = oc + wn * 32 + frow;
        #pragma unroll
        for (int m = 0; m < 16; ++m) {
            #pragma unroll
            for (int reg = 0; reg < 4; ++reg) {
                int r = m * 16 + fks * 4 + reg;
                if (r < rows) {
                    int tok = perm[c0 + r];
                    float* orow = out + (size_t)tok * ODIM + col0;
                    orow[0]  = acc[m][0][reg];
                    orow[16] = acc[m][1][reg];
                }
            }
        }
#undef ISSUE_A
#undef CVTWRITE_A
#undef ISSUE_B
#undef BW1
#undef CVTWRITE_B
#undef STEP
    }
#undef BARRIER
}

extern "C" void kernel_launch(void* const* d_in, const int* in_sizes, int n_in,
                              void* d_out, int out_size, void* d_ws, size_t ws_size,
                              hipStream_t stream) {
    const float* inp    = (const float*)d_in[0];
    const int*   gate   = (const int*)d_in[1];
    const float* weight = (const float*)d_in[2];
    float*       out    = (float*)d_out;

    int* perm = (int*)d_ws;                          // 2048 ints
    int* offs = perm + NTOK;                         // 17 ints
    unsigned short* A2 = (unsigned short*)((char*)d_ws + 16384);
    const size_t need = 16384 + (size_t)NTOK * KDIM * 2;   // ~4.2 MB
    const bool pre = (ws_size >= need);              // host-side, deterministic

    moe_sort<<<1, 256, 0, stream>>>(gate, perm, offs);
    if (pre) {
        moe_cvt<<<NTOK, 256, 0, stream>>>(inp, perm, A2);
        moe_gemm<true><<<NBLK, 512, 0, stream>>>(inp, A2, weight, perm, offs, out);
    } else {
        moe_gemm<false><<<NBLK, 512, 0, stream>>>(inp, A2, weight, perm, offs, out);
    }
}

// Round 7
// 112.873 us; speedup vs baseline: 1.0422x; 1.0422x over previous
//
#include <hip/hip_runtime.h>
#include <hip/hip_bf16.h>

#define NEXP 16
#define KDIM 1024
#define ODIM 4096
#define NTOK 2048

#define BM   256                    // token rows resident per block
#define BN   256                    // output cols per block (8 waves x 32)
#define KC   32                     // K per phase (= one MFMA K)
#define NPH  (KDIM / KC)            // 32 phases
#define NBLK (NEXP * (ODIM / BN))   // 256 blocks = 1 per CU

// LDS map (bytes): B stage s at s*32768 ([256 r][8 h][16B] fp32, h holds src
// half-oct h^(r&7)); A stage s at 98304+s*16384 ([4 g][256 r][16B] bf16).
#define LDSB_OFF(s) ((s) * 32768)
#define LDSA_OFF(s) (98304 + (s) * 16384)
#define LDS_BYTES   (3 * 32768 + 3 * 16384)   // 144 KB

typedef __attribute__((ext_vector_type(8))) short short8;
typedef __attribute__((ext_vector_type(4))) float f32x4;

typedef __attribute__((address_space(3))) unsigned lds_uint;
typedef const __attribute__((address_space(1))) unsigned glob_uint;

__device__ __forceinline__ void gload16(const void* g, void* l) {
    __builtin_amdgcn_global_load_lds((glob_uint*)g, (lds_uint*)l, 16, 0, 0);
}

__device__ __forceinline__ unsigned short f2bf(float f) {
    __hip_bfloat16 h = __float2bfloat16(f);
    return __builtin_bit_cast(unsigned short, h);
}

__device__ __forceinline__ short8 pack8(float4 a, float4 b) {
    short8 r;
    r[0] = (short)f2bf(a.x); r[1] = (short)f2bf(a.y);
    r[2] = (short)f2bf(a.z); r[3] = (short)f2bf(a.w);
    r[4] = (short)f2bf(b.x); r[5] = (short)f2bf(b.y);
    r[6] = (short)f2bf(b.z); r[7] = (short)f2bf(b.w);
    return r;
}

#define SFENCE() __builtin_amdgcn_sched_barrier(0)
#define WAITVM(N) do { SFENCE(); \
        asm volatile("s_waitcnt vmcnt(" #N ")" ::: "memory"); SFENCE(); } while (0)
#define WAITLG() do { SFENCE(); \
        asm volatile("s_waitcnt lgkmcnt(0)" ::: "memory"); SFENCE(); } while (0)

// ---------------------------------------------------------------------------
// Kernel 1: deterministic counting sort of tokens by expert (unchanged).
// ---------------------------------------------------------------------------
__global__ __launch_bounds__(256) void moe_sort(const int* __restrict__ gate,
                                                int* __restrict__ perm,
                                                int* __restrict__ offs) {
    __shared__ int lgate[NTOK];
    __shared__ int hist[256][NEXP + 1];
    __shared__ int base[NEXP];
    const int t = threadIdx.x;
    for (int i = t; i < NTOK; i += 256) lgate[i] = gate[i];
    #pragma unroll
    for (int e = 0; e < NEXP; ++e) hist[t][e] = 0;
    __syncthreads();
    const int TPT = NTOK / 256;
    for (int j = 0; j < TPT; ++j) hist[t][lgate[t * TPT + j]]++;
    __syncthreads();
    if (t < NEXP) {
        int s = 0;
        for (int i = 0; i < 256; ++i) { int v = hist[i][t]; hist[i][t] = s; s += v; }
        base[t] = s;
    }
    __syncthreads();
    if (t == 0) {
        int s = 0;
        for (int e = 0; e < NEXP; ++e) { int v = base[e]; base[e] = s; offs[e] = s; s += v; }
        offs[NEXP] = s;
    }
    __syncthreads();
    #pragma unroll
    for (int e = 0; e < NEXP; ++e) hist[t][e] += base[e];
    for (int j = 0; j < TPT; ++j) {
        int tok = t * TPT + j;
        int e = lgate[tok];
        int pos = hist[t][e]++;
        perm[pos] = tok;
    }
}

// ---------------------------------------------------------------------------
// Kernel 1.5: gather+convert A to bf16, OCT-MAJOR: A2T2[oct=k>>3][pos][8 bf16]
// so the GEMM's A staging is a linear 16B-granule copy (global_load_lds-able).
// Block (oct o, pos-chunk pc): coalesced 16B writes; gather reads per token.
// ---------------------------------------------------------------------------
__global__ __launch_bounds__(256) void moe_cvt(const float* __restrict__ inp,
                                               const int* __restrict__ perm,
                                               unsigned short* __restrict__ A2T2) {
    const int o   = blockIdx.x;                 // 0..127 k-octet
    const int pos = blockIdx.y * 256 + threadIdx.x;
    const int tok = perm[pos];
    const float4* s = (const float4*)(inp + (size_t)tok * KDIM + o * 8);
    float4 v0 = s[0], v1 = s[1];
    *(short8*)(A2T2 + ((size_t)o * NTOK + pos) * 8) = pack8(v0, v1);
}

// ---------------------------------------------------------------------------
// Kernel 2: A-resident grouped GEMM, 3-stage global_load_lds pipeline with
// counted vmcnt (T3+T4): phase p prefetches stage p+2 (6 gloads/wave), does
// MFMA on stage p, then waits vmcnt(6) -> stage p+1's loads complete while
// stage p+2's SIX loads stay in flight ACROSS the barrier. Never drains.
// W is fp32 in LDS (src pre-swizzled h^(r&7), rule #21); bf16 cvt happens at
// fragment read (pack8) on the 95%-idle VALU. W read exactly once chip-wide.
// ---------------------------------------------------------------------------
template <bool PRE>
__global__ __launch_bounds__(512, 1) void moe_gemm(
    const float* __restrict__ inp,
    const unsigned short* __restrict__ A2T2,
    const float* __restrict__ weight,
    const int* __restrict__ perm,
    const int* __restrict__ offs,
    float* __restrict__ out)
{
    const int bid = blockIdx.x;
    const int v   = (bid & 7) * (NBLK / 8) + (bid >> 3); // 32 consec per XCD
    const int e   = v >> 4;                              // 16 oc-tiles/expert
    const int oc  = (v & 15) * BN;

    const int beg = offs[e], end = offs[e + 1];
    const int nall = end - beg;
    if (nall <= 0) return;

    __shared__ char lds[LDS_BYTES];

    const int t    = threadIdx.x;      // 0..511
    const int lane = t & 63;
    const int w    = t >> 6;           // wave = col-group (wn)
    const int frow = lane & 15;
    const int fks  = lane >> 4;        // 0..3 = k-octet of the fragment

    // ---- B staging: granule s = q*512+t -> r=q*64+(t>>3), h=t&7;
    //      source half-oct hs = h ^ (r&7) (r&7 == (t>>3)&7, q-invariant) ----
    const int srb = t >> 3;
    const int hs  = (t & 7) ^ ((t >> 3) & 7);
    const float* bsrc[4];
    #pragma unroll
    for (int q = 0; q < 4; ++q)
        bsrc[q] = weight + ((size_t)e * ODIM + oc + q * 64 + srb) * KDIM + hs * 4;

#define ISSUE_B(bB, kc) {                                                     \
        _Pragma("unroll")                                                     \
        for (int q = 0; q < 4; ++q)                                           \
            gload16(bsrc[q] + (kc), (bB) + (q * 512 + w * 64) * 16);          \
    }
// A (PRE): granules s=t (g=t>>8, r=t&255) and s=t+512 (g+2). Linear copy.
#define ISSUE_A(bA, ck) {                                                     \
        gload16(asrc0 + (size_t)(ck) * (4 * NTOK * 8), (bA) + w * 1024);      \
        gload16(asrc1 + (size_t)(ck) * (4 * NTOK * 8), (bA) + 8192 + w * 1024);\
    }
// A (!PRE): reg-stage from inp fp32 (depth-1), write bf16 to same layout.
#define NLOAD_A(kc) {                                                         \
        A0a = *(const float4*)(afsrc + (kc));                                 \
        A0b = *(const float4*)(afsrc + (kc) + 4);                             \
        A1a = *(const float4*)(afsrc + (kc) + 16);                            \
        A1b = *(const float4*)(afsrc + (kc) + 20);                            \
    }
#define NWRITE_A(bA) {                                                        \
        *(short8*)((bA) + t * 16)        = pack8(A0a, A0b);                   \
        *(short8*)((bA) + 8192 + t * 16) = pack8(A1a, A1b);                   \
    }
#define STEP(bB, bA) {                                                        \
        short8 bfr0, bfr1;                                                    \
        {                                                                     \
            int rB = w * 32 + frow;                                           \
            int x  = rB & 7;                                                  \
            float4 flo = *(const float4*)((bB) + rB * 128 + (((2*fks)  ^x)*16)); \
            float4 fhi = *(const float4*)((bB) + rB * 128 + (((2*fks+1)^x)*16)); \
            bfr0 = pack8(flo, fhi);                                           \
            rB += 16; x = rB & 7;                                             \
            flo = *(const float4*)((bB) + rB * 128 + (((2*fks)  ^x)*16));     \
            fhi = *(const float4*)((bB) + rB * 128 + (((2*fks+1)^x)*16));     \
            bfr1 = pack8(flo, fhi);                                           \
        }                                                                     \
        _Pragma("unroll")                                                     \
        for (int m = 0; m < 16; ++m) {                                        \
            if (m < mfrags) {                                                 \
                int row = m * 16 + frow;                                      \
                short8 af = *(const short8*)((bA) + (fks * 256 + row) * 16);  \
                acc[m][0] = __builtin_amdgcn_mfma_f32_16x16x32_bf16(af, bfr0, acc[m][0], 0, 0, 0); \
                acc[m][1] = __builtin_amdgcn_mfma_f32_16x16x32_bf16(af, bfr1, acc[m][1], 0, 0, 0); \
            }                                                                 \
        }                                                                     \
    }

    for (int base = 0; base < nall; base += BM) {
        const int rows = (nall - base < BM) ? (nall - base) : BM;
        const int c0   = beg + base;
        const int mfrags = (rows + 15) >> 4;

        int rcl = t & 255; if (rcl > rows - 1) rcl = rows - 1;
        const unsigned short* asrc0 = 0;
        const unsigned short* asrc1 = 0;
        const float* afsrc = 0;
        if (PRE) {
            const int g0 = t >> 8;                       // 0..1
            asrc0 = A2T2 + ((size_t)g0       * NTOK + (c0 + rcl)) * 8;
            asrc1 = A2T2 + ((size_t)(g0 + 2) * NTOK + (c0 + rcl)) * 8;
        } else {
            afsrc = inp + (size_t)perm[c0 + rcl] * KDIM + (t >> 8) * 8;
        }

        f32x4 acc[16][2];
        #pragma unroll
        for (int m = 0; m < 16; ++m) {
            acc[m][0] = (f32x4){0.f, 0.f, 0.f, 0.f};
            acc[m][1] = (f32x4){0.f, 0.f, 0.f, 0.f};
        }
        float4 A0a, A0b, A1a, A1b;   // !PRE staging regs (single set)

        int s0 = 0, s1 = 1, s2 = 2;  // stage rotation (p, p+1, p+2)

        // ---- prologue ----
        __builtin_amdgcn_s_barrier();           // prior chunk fully consumed
        if (PRE) {
            ISSUE_B(lds + LDSB_OFF(0), 0); ISSUE_A(lds + LDSA_OFF(0), 0);
            ISSUE_B(lds + LDSB_OFF(1), KC); ISSUE_A(lds + LDSA_OFF(1), 1);
            WAITVM(6);                          // stage0 landed, stage1 in flight
            __builtin_amdgcn_s_barrier();
        } else {
            ISSUE_B(lds + LDSB_OFF(0), 0);
            NLOAD_A(0);
            ISSUE_B(lds + LDSB_OFF(1), KC);
            NWRITE_A(lds + LDSA_OFF(0));        // compiler-counted vmcnt wait
            WAITVM(4);
            WAITLG();
            __builtin_amdgcn_s_barrier();
        }

        // ---- 32 phases ----
        for (int p = 0; p < NPH; ++p) {
            char* const bB0 = lds + LDSB_OFF(s0);
            char* const bA0 = lds + LDSA_OFF(s0);
            char* const bB2 = lds + LDSB_OFF(s2);
            char* const bA2 = lds + LDSA_OFF(s2);
            char* const bA1 = lds + LDSA_OFF(s1);
            if (PRE) {
                if (p + 2 < NPH) { ISSUE_B(bB2, (p + 2) * KC); ISSUE_A(bA2, p + 2); }
                SFENCE();
                STEP(bB0, bA0);
                if (p + 2 < NPH)      { WAITVM(6); }
                else if (p + 1 < NPH) { WAITVM(0); }
                if (p + 1 < NPH) __builtin_amdgcn_s_barrier();
            } else {
                if (p + 2 < NPH) ISSUE_B(bB2, (p + 2) * KC);
                if (p + 1 < NPH) NLOAD_A((p + 1) * KC);
                SFENCE();
                STEP(bB0, bA0);
                if (p + 1 < NPH) NWRITE_A(bA1);   // auto-counted vmcnt wait
                if (p + 2 < NPH)      { WAITVM(4); }
                else if (p + 1 < NPH) { WAITVM(0); }
                if (p + 1 < NPH) { WAITLG(); __builtin_amdgcn_s_barrier(); }
            }
            int tmp = s0; s0 = s1; s1 = s2; s2 = tmp;
        }

        // ---- epilogue: C layout col=lane&15, row=(lane>>4)*4+reg ----
        const int col0 = oc + w * 32 + frow;
        #pragma unroll
        for (int m = 0; m < 16; ++m) {
            #pragma unroll
            for (int reg = 0; reg < 4; ++reg) {
                int r = m * 16 + fks * 4 + reg;
                if (r < rows) {
                    int tok = perm[c0 + r];
                    float* orow = out + (size_t)tok * ODIM + col0;
                    orow[0]  = acc[m][0][reg];
                    orow[16] = acc[m][1][reg];
                }
            }
        }
    }
#undef ISSUE_B
#undef ISSUE_A
#undef NLOAD_A
#undef NWRITE_A
#undef STEP
}

extern "C" void kernel_launch(void* const* d_in, const int* in_sizes, int n_in,
                              void* d_out, int out_size, void* d_ws, size_t ws_size,
                              hipStream_t stream) {
    const float* inp    = (const float*)d_in[0];
    const int*   gate   = (const int*)d_in[1];
    const float* weight = (const float*)d_in[2];
    float*       out    = (float*)d_out;

    int* perm = (int*)d_ws;                          // 2048 ints
    int* offs = perm + NTOK;                         // 17 ints
    unsigned short* A2T2 = (unsigned short*)((char*)d_ws + 16384);
    const size_t need = 16384 + (size_t)NTOK * KDIM * 2;   // ~4.2 MB
    const bool pre = (ws_size >= need);              // host-side, deterministic

    moe_sort<<<1, 256, 0, stream>>>(gate, perm, offs);
    if (pre) {
        dim3 cg(KDIM / 8, NTOK / 256);               // 128 x 8
        moe_cvt<<<cg, 256, 0, stream>>>(inp, perm, A2T2);
        moe_gemm<true><<<NBLK, 512, 0, stream>>>(inp, A2T2, weight, perm, offs, out);
    } else {
        moe_gemm<false><<<NBLK, 512, 0, stream>>>(inp, A2T2, weight, perm, offs, out);
    }
}

// Round 8
// 106.712 us; speedup vs baseline: 1.1023x; 1.0577x over previous
//
#include <hip/hip_runtime.h>
#include <hip/hip_bf16.h>

#define NEXP 16
#define KDIM 1024
#define ODIM 4096
#define NTOK 2048

#define BM   256                    // token rows per block (covers n_e)
#define BN   128                    // output cols per block (4 col-groups x 32)
#define KC   32                     // K per phase
#define NPH  (KDIM / KC)            // 32 phases
#define NBLK (NEXP * (ODIM / BN))   // 512 blocks = 2 per CU

typedef __attribute__((ext_vector_type(8))) short short8;
typedef __attribute__((ext_vector_type(4))) float f32x4;

typedef __attribute__((address_space(3))) unsigned lds_uint;
typedef const __attribute__((address_space(1))) unsigned glob_uint;

__device__ __forceinline__ void gload16(const void* g, void* l) {
    __builtin_amdgcn_global_load_lds((glob_uint*)g, (lds_uint*)l, 16, 0, 0);
}

__device__ __forceinline__ unsigned short f2bf(float f) {
    __hip_bfloat16 h = __float2bfloat16(f);
    return __builtin_bit_cast(unsigned short, h);
}

__device__ __forceinline__ short8 pack8(float4 a, float4 b) {
    short8 r;
    r[0] = (short)f2bf(a.x); r[1] = (short)f2bf(a.y);
    r[2] = (short)f2bf(a.z); r[3] = (short)f2bf(a.w);
    r[4] = (short)f2bf(b.x); r[5] = (short)f2bf(b.y);
    r[6] = (short)f2bf(b.z); r[7] = (short)f2bf(b.w);
    return r;
}

#define SFENCE() __builtin_amdgcn_sched_barrier(0)
#define WAITVM(N) do { SFENCE(); \
        asm volatile("s_waitcnt vmcnt(" #N ")" ::: "memory"); SFENCE(); } while (0)
#define WAITLG() do { SFENCE(); \
        asm volatile("s_waitcnt lgkmcnt(0)" ::: "memory"); SFENCE(); } while (0)

// ---------------------------------------------------------------------------
// Kernel 1: deterministic counting sort of tokens by expert (unchanged).
// ---------------------------------------------------------------------------
__global__ __launch_bounds__(256) void moe_sort(const int* __restrict__ gate,
                                                int* __restrict__ perm,
                                                int* __restrict__ offs) {
    __shared__ int lgate[NTOK];
    __shared__ int hist[256][NEXP + 1];
    __shared__ int base[NEXP];
    const int t = threadIdx.x;
    for (int i = t; i < NTOK; i += 256) lgate[i] = gate[i];
    #pragma unroll
    for (int e = 0; e < NEXP; ++e) hist[t][e] = 0;
    __syncthreads();
    const int TPT = NTOK / 256;
    for (int j = 0; j < TPT; ++j) hist[t][lgate[t * TPT + j]]++;
    __syncthreads();
    if (t < NEXP) {
        int s = 0;
        for (int i = 0; i < 256; ++i) { int v = hist[i][t]; hist[i][t] = s; s += v; }
        base[t] = s;
    }
    __syncthreads();
    if (t == 0) {
        int s = 0;
        for (int e = 0; e < NEXP; ++e) { int v = base[e]; base[e] = s; offs[e] = s; s += v; }
        offs[NEXP] = s;
    }
    __syncthreads();
    #pragma unroll
    for (int e = 0; e < NEXP; ++e) hist[t][e] += base[e];
    for (int j = 0; j < TPT; ++j) {
        int tok = t * TPT + j;
        int e = lgate[tok];
        int pos = hist[t][e]++;
        perm[pos] = tok;
    }
}

// ---------------------------------------------------------------------------
// Kernel 1.5: gather+convert A to bf16, oct-major A2T2[oct][pos][8 bf16]
// so GEMM A-staging is a linear 16B-granule global_load_lds copy (unchanged).
// ---------------------------------------------------------------------------
__global__ __launch_bounds__(256) void moe_cvt(const float* __restrict__ inp,
                                               const int* __restrict__ perm,
                                               unsigned short* __restrict__ A2T2) {
    const int o   = blockIdx.x;                 // 0..127 k-octet
    const int pos = blockIdx.y * 256 + threadIdx.x;
    const int tok = perm[pos];
    const float4* s = (const float4*)(inp + (size_t)tok * KDIM + o * 8);
    float4 v0 = s[0], v1 = s[1];
    *(short8*)(A2T2 + ((size_t)o * NTOK + pos) * 8) = pack8(v0, v1);
}

// ---------------------------------------------------------------------------
// Kernel 2: grouped GEMM, 2 blocks/CU co-residency (m97/m114 regime).
// Block = (expert, 128 out-cols); 8 waves = 2 row-halves x 4 col-groups.
// LDS 64 KB/block: B fp32 dbuf [2][128][32] (granule source-swizzled
// p^(row&7), rule 21) + A bf16 dbuf [2][4][256][8] (oct-major, linear).
// Per phase: STEP -> lgkm barrier -> issue p+2 into freed buffer ->
// vmcnt(4) (p+2's 4 loads stay in flight across the barrier) -> barrier.
// The co-resident block covers any residual stall (m114).
// W read exactly once chip-wide; bf16 cvt of B at fragment read (idle VALU).
// ---------------------------------------------------------------------------
template <bool PRE>
__global__ __launch_bounds__(512, 4) void moe_gemm(
    const float* __restrict__ inp,
    const unsigned short* __restrict__ A2T2,
    const float* __restrict__ weight,
    const int* __restrict__ perm,
    const int* __restrict__ offs,
    float* __restrict__ out)
{
    const int bid = blockIdx.x;
    const int v   = (bid & 7) * (NBLK / 8) + (bid >> 3); // 64 consec/XCD = 2 experts
    const int e   = v >> 5;                              // 32 oc-tiles per expert
    const int oc  = (v & 31) * BN;

    const int beg = offs[e], end = offs[e + 1];
    const int nall = end - beg;
    if (nall <= 0) return;

    __shared__ float Bs[2][BN][KC];        // 32 KB fp32 (granule-swizzled)
    __shared__ short As[2][4][BM][8];      // 32 KB bf16 (oct-major, linear)

    const int t    = threadIdx.x;          // 0..511
    const int lane = t & 63;
    const int w    = t >> 6;               // 0..7
    const int wm   = w >> 2;               // row half (128 rows)
    const int wn   = w & 3;                // col group (32 cols)
    const int frow = lane & 15;
    const int fks  = lane >> 4;            // 0..3 = k-octet

    // ---- B staging: granule s in {t, t+512}; row=s>>3, slot=s&7.
    //      source granule = slot ^ (row&7)  (row&7 identical for both s) ----
    const int brow = t >> 3;               // 0..63
    const int hs   = (t & 7) ^ ((t >> 3) & 7);
    const float* bsrc0 = weight + ((size_t)e * ODIM + oc + brow) * KDIM + hs * 4;
    const float* bsrc1 = bsrc0 + (size_t)64 * KDIM;

#define ISSUE_B(buf, kc) {                                                    \
        gload16(bsrc0 + (kc), (char*)&Bs[buf][0][0] + t * 16);                \
        gload16(bsrc1 + (kc), (char*)&Bs[buf][0][0] + 8192 + t * 16);         \
    }
// A (PRE): granules s in {t, t+512}: g = s>>8 (oct within KC), r = s&255.
#define ISSUE_A(buf, p) {                                                     \
        gload16(asrc0 + (size_t)(p) * (4 * NTOK * 8),                         \
                (char*)&As[buf][0][0][0] + t * 16);                           \
        gload16(asrc1 + (size_t)(p) * (4 * NTOK * 8),                         \
                (char*)&As[buf][0][0][0] + 8192 + t * 16);                    \
    }
// A (!PRE): reg-stage fp32 -> bf16 (fallback, drain pipeline).
#define NLOAD_A(p) {                                                          \
        A0a = *(const float4*)(afsrc + (p) * KC);                             \
        A0b = *(const float4*)(afsrc + (p) * KC + 4);                         \
        A1a = *(const float4*)(afsrc + (p) * KC + 16);                        \
        A1b = *(const float4*)(afsrc + (p) * KC + 20);                        \
    }
#define NWRITE_A(buf) {                                                       \
        *(short8*)((char*)&As[buf][0][0][0] + t * 16)        = pack8(A0a, A0b); \
        *(short8*)((char*)&As[buf][0][0][0] + 8192 + t * 16) = pack8(A1a, A1b); \
    }
#define STEP(buf) {                                                           \
        short8 bfr0, bfr1;                                                    \
        {                                                                     \
            int rB = wn * 32 + frow;                                          \
            int x  = rB & 7;                                                  \
            float4 lo = *(const float4*)((const char*)&Bs[buf][0][0]          \
                         + rB * 128 + (((2 * fks)     ^ x) * 16));            \
            float4 hi = *(const float4*)((const char*)&Bs[buf][0][0]          \
                         + rB * 128 + (((2 * fks + 1) ^ x) * 16));            \
            bfr0 = pack8(lo, hi);                                             \
            rB += 16;                                                         \
            lo = *(const float4*)((const char*)&Bs[buf][0][0]                 \
                         + rB * 128 + (((2 * fks)     ^ x) * 16));            \
            hi = *(const float4*)((const char*)&Bs[buf][0][0]                 \
                         + rB * 128 + (((2 * fks + 1) ^ x) * 16));            \
            bfr1 = pack8(lo, hi);                                             \
        }                                                                     \
        _Pragma("unroll")                                                     \
        for (int m = 0; m < 8; ++m) {                                         \
            if (m * 16 < mmax) {                                              \
                int row = wm * 128 + m * 16 + frow;                           \
                short8 af = *(const short8*)((const char*)&As[buf][0][0][0]   \
                             + fks * 4096 + row * 16);                        \
                acc[m][0] = __builtin_amdgcn_mfma_f32_16x16x32_bf16(af, bfr0, acc[m][0], 0, 0, 0); \
                acc[m][1] = __builtin_amdgcn_mfma_f32_16x16x32_bf16(af, bfr1, acc[m][1], 0, 0, 0); \
            }                                                                 \
        }                                                                     \
    }

    for (int base = 0; base < nall; base += BM) {
        const int rows = (nall - base < BM) ? (nall - base) : BM;
        const int c0   = beg + base;
        const int mmax = rows - wm * 128;      // wave-uniform active m extent

        int rcl = t & 255; if (rcl > rows - 1) rcl = rows - 1;
        const unsigned short* asrc0 = 0;
        const unsigned short* asrc1 = 0;
        const float* afsrc = 0;
        if (PRE) {
            const int g0 = t >> 8;             // 0..1
            asrc0 = A2T2 + ((size_t)g0       * NTOK + (c0 + rcl)) * 8;
            asrc1 = A2T2 + ((size_t)(g0 + 2) * NTOK + (c0 + rcl)) * 8;
        } else {
            afsrc = inp + (size_t)perm[c0 + rcl] * KDIM + (t >> 8) * 8;
        }

        f32x4 acc[8][2];
        #pragma unroll
        for (int m = 0; m < 8; ++m) {
            acc[m][0] = (f32x4){0.f, 0.f, 0.f, 0.f};
            acc[m][1] = (f32x4){0.f, 0.f, 0.f, 0.f};
        }
        float4 A0a, A0b, A1a, A1b;             // !PRE staging regs

        // ---- chunk top: prior buffer consumers done ----
        WAITLG();
        __builtin_amdgcn_s_barrier();

        if (PRE) {
            ISSUE_B(0, 0);  ISSUE_A(0, 0);
            ISSUE_B(1, KC); ISSUE_A(1, 1);
            WAITVM(4);                          // stage0 landed, stage1 in flight
            __builtin_amdgcn_s_barrier();
            for (int p = 0; p < NPH; ++p) {
                const int cur = p & 1;
                STEP(cur);
                if (p + 1 < NPH) {
                    WAITLG();
                    __builtin_amdgcn_s_barrier();        // reads of cur done
                    if (p + 2 < NPH) {
                        ISSUE_B(cur, (p + 2) * KC);
                        ISSUE_A(cur, p + 2);
                        WAITVM(4);               // p+1 landed; p+2's 4 in flight
                    } else {
                        WAITVM(0);
                    }
                    __builtin_amdgcn_s_barrier();        // p+1 data ready
                }
            }
        } else {
            NLOAD_A(0); ISSUE_B(0, 0);  NWRITE_A(0);
            NLOAD_A(1); ISSUE_B(1, KC); NWRITE_A(1);
            WAITVM(0); WAITLG();
            __builtin_amdgcn_s_barrier();
            for (int p = 0; p < NPH; ++p) {
                const int cur = p & 1;
                if (p + 2 < NPH) NLOAD_A(p + 2);
                STEP(cur);
                if (p + 1 < NPH) {
                    WAITLG();
                    __builtin_amdgcn_s_barrier();
                    if (p + 2 < NPH) { ISSUE_B(cur, (p + 2) * KC); NWRITE_A(cur); }
                    WAITVM(0); WAITLG();
                    __builtin_amdgcn_s_barrier();
                }
            }
        }

        // ---- epilogue: C layout col=lane&15, row=(lane>>4)*4+reg ----
        const int col0 = oc + wn * 32 + frow;
        #pragma unroll
        for (int m = 0; m < 8; ++m) {
            #pragma unroll
            for (int reg = 0; reg < 4; ++reg) {
                int r = wm * 128 + m * 16 + fks * 4 + reg;
                if (r < rows) {
                    int tok = perm[c0 + r];
                    float* orow = out + (size_t)tok * ODIM + col0;
                    orow[0]  = acc[m][0][reg];
                    orow[16] = acc[m][1][reg];
                }
            }
        }
    }
#undef ISSUE_B
#undef ISSUE_A
#undef NLOAD_A
#undef NWRITE_A
#undef STEP
}

extern "C" void kernel_launch(void* const* d_in, const int* in_sizes, int n_in,
                              void* d_out, int out_size, void* d_ws, size_t ws_size,
                              hipStream_t stream) {
    const float* inp    = (const float*)d_in[0];
    const int*   gate   = (const int*)d_in[1];
    const float* weight = (const float*)d_in[2];
    float*       out    = (float*)d_out;

    int* perm = (int*)d_ws;                          // 2048 ints
    int* offs = perm + NTOK;                         // 17 ints
    unsigned short* A2T2 = (unsigned short*)((char*)d_ws + 16384);
    const size_t need = 16384 + (size_t)NTOK * KDIM * 2;   // ~4.2 MB
    const bool pre = (ws_size >= need);              // host-side, deterministic

    moe_sort<<<1, 256, 0, stream>>>(gate, perm, offs);
    if (pre) {
        dim3 cg(KDIM / 8, NTOK / 256);               // 128 x 8
        moe_cvt<<<cg, 256, 0, stream>>>(inp, perm, A2T2);
        moe_gemm<true><<<NBLK, 512, 0, stream>>>(inp, A2T2, weight, perm, offs, out);
    } else {
        moe_gemm<false><<<NBLK, 512, 0, stream>>>(inp, A2T2, weight, perm, offs, out);
    }
}